// Round 8
// baseline (500.341 us; speedup 1.0000x reference)
//
#include <hip/hip_runtime.h>
#include <math.h>

#define NB 8
#define NS 32768
#define SEQ 128
#define DIM 128
#define KER 512
#define PI_D 3.14159265358979323846

#define ALOAD(p)     __hip_atomic_load((p), __ATOMIC_RELAXED, __HIP_MEMORY_SCOPE_AGENT)
#define ASTORE(p, v) __hip_atomic_store((p), (v), __ATOMIC_RELAXED, __HIP_MEMORY_SCOPE_AGENT)

typedef __attribute__((ext_vector_type(8))) short bfrag;
typedef __attribute__((ext_vector_type(16))) float f32x16;

// ---------------- pos encoding table + hamming window ----------------
__global__ void pos_k(float* __restrict__ posT, float* __restrict__ ham) {
    int t = threadIdx.x; // 512
    if (t < 128) {
        double p = (double)((float)(-1.0 + 2.0 * (double)t / 127.0));
        posT[t * 33 + 0] = (float)p;
        for (int i = 0; i < 16; ++i) {
            double a = ldexp(p, i) * PI_D;
            posT[t * 33 + 1 + 2 * i] = (float)sin(a);
            posT[t * 33 + 2 + 2 * i] = (float)cos(a);
        }
    }
    ham[t] = (float)(0.54 - 0.46 * cos(2.0 * PI_D * (double)t / 511.0));
}

// ---------------- f32 -> bf16 hi/lo split (RNE) ----------------
__device__ __forceinline__ unsigned short bf_rne(float v) {
    unsigned int u = __float_as_uint(v);
    unsigned int r = u + 0x7FFFu + ((u >> 16) & 1u);
    return (unsigned short)(r >> 16);
}
__global__ void bfsplit_k(const float* __restrict__ src, unsigned short* __restrict__ hi,
                          unsigned short* __restrict__ lo, int n) {
    int i = blockIdx.x * 256 + threadIdx.x;
    if (i < n) {
        float v = src[i];
        unsigned short h = bf_rne(v);
        float hf = __uint_as_float(((unsigned int)h) << 16);
        hi[i] = h;
        lo[i] = bf_rne(v - hf);
    }
}

// ---------------- filter pack: F[128][512] -> fragment-ordered bf16 hi/lo ----------------
__global__ void fpack_k(const float* __restrict__ F, unsigned short* __restrict__ Fph,
                        unsigned short* __restrict__ Fpl) {
    int idx = blockIdx.x * 256 + threadIdx.x; // 65536
    int e = idx & 7, lane = (idx >> 3) & 63, step = (idx >> 9) & 31, mt = idx >> 14;
    int row = mt * 32 + (lane & 31);
    int k = step * 16 + (lane >> 5) * 8 + e;
    float v = F[row * 512 + k];
    unsigned short h = bf_rne(v);
    float hf = __uint_as_float(((unsigned int)h) << 16);
    Fph[idx] = h;
    Fpl[idx] = bf_rne(v - hf);
}

// ---------------- conv + abs + 256-chunk pool via split-bf16 MFMA ----------------
__global__ void __launch_bounds__(512) conv_mfma_k(
        const unsigned short* __restrict__ xhi, const unsigned short* __restrict__ xlo,
        const unsigned short* __restrict__ Fph, const unsigned short* __restrict__ Fpl,
        float* __restrict__ P) {
    int c = blockIdx.x, b = blockIdx.y;
    int t = threadIdx.x;
    __shared__ __align__(16) unsigned short xsh[8][776];
    __shared__ __align__(16) unsigned short xsl[8][776];
    __shared__ float Pp[128];
    int base = c * 256 - 256;
    for (int j = t; j < 768; j += 512) {
        int gi = base + j;
        unsigned short h = 0, l = 0;
        if (gi >= 0 && gi < NS) { h = xhi[b * NS + gi]; l = xlo[b * NS + gi]; }
#pragma unroll
        for (int r = 0; r < 8; ++r) {
            int slot = j - r;
            if (slot >= 0) { xsh[r][slot] = h; xsl[r][slot] = l; }
        }
    }
    if (t < 128) Pp[t] = 0.f;
    __syncthreads();

    int wid = t >> 6, lane = t & 63;
    int col = lane & 31, g = lane >> 5;
    int mbase = (wid & 1) * 64;
    int nbase = (wid >> 1) * 64;
    int rsel = col & 7;
    int p0 = nbase + col + 8 * g - rsel;

    const bfrag* bh0 = (const bfrag*)&xsh[rsel][p0];
    const bfrag* bl0 = (const bfrag*)&xsl[rsel][p0];
    const bfrag* bh1 = (const bfrag*)&xsh[rsel][p0 + 32];
    const bfrag* bl1 = (const bfrag*)&xsl[rsel][p0 + 32];

    int mt0 = (wid & 1) * 2;
    const unsigned short* aph = Fph + (size_t)mt0 * 16384 + lane * 8;
    const unsigned short* apl = Fpl + (size_t)mt0 * 16384 + lane * 8;

    f32x16 c00, c01, c10, c11;
#pragma unroll
    for (int r = 0; r < 16; ++r) { c00[r] = 0.f; c01[r] = 0.f; c10[r] = 0.f; c11[r] = 0.f; }

    bfrag ch0 = *(const bfrag*)(aph);
    bfrag ch1 = *(const bfrag*)(aph + 16384);
    bfrag cl0 = *(const bfrag*)(apl);
    bfrag cl1 = *(const bfrag*)(apl + 16384);
    bfrag dh0 = bh0[0], dl0 = bl0[0], dh1 = bh1[0], dl1 = bl1[0];
#pragma unroll 2
    for (int step = 0; step < 32; ++step) {
        int sn = (step < 31) ? step + 1 : 31;
        bfrag nh0 = *(const bfrag*)(aph + sn * 512);
        bfrag nh1 = *(const bfrag*)(aph + 16384 + sn * 512);
        bfrag nl0 = *(const bfrag*)(apl + sn * 512);
        bfrag nl1 = *(const bfrag*)(apl + 16384 + sn * 512);
        bfrag mh0 = bh0[2 * sn], ml0 = bl0[2 * sn];
        bfrag mh1 = bh1[2 * sn], ml1 = bl1[2 * sn];
        c00 = __builtin_amdgcn_mfma_f32_32x32x16_bf16(ch0, dh0, c00, 0, 0, 0);
        c00 = __builtin_amdgcn_mfma_f32_32x32x16_bf16(ch0, dl0, c00, 0, 0, 0);
        c00 = __builtin_amdgcn_mfma_f32_32x32x16_bf16(cl0, dh0, c00, 0, 0, 0);
        c01 = __builtin_amdgcn_mfma_f32_32x32x16_bf16(ch0, dh1, c01, 0, 0, 0);
        c01 = __builtin_amdgcn_mfma_f32_32x32x16_bf16(ch0, dl1, c01, 0, 0, 0);
        c01 = __builtin_amdgcn_mfma_f32_32x32x16_bf16(cl0, dh1, c01, 0, 0, 0);
        c10 = __builtin_amdgcn_mfma_f32_32x32x16_bf16(ch1, dh0, c10, 0, 0, 0);
        c10 = __builtin_amdgcn_mfma_f32_32x32x16_bf16(ch1, dl0, c10, 0, 0, 0);
        c10 = __builtin_amdgcn_mfma_f32_32x32x16_bf16(cl1, dh0, c10, 0, 0, 0);
        c11 = __builtin_amdgcn_mfma_f32_32x32x16_bf16(ch1, dh1, c11, 0, 0, 0);
        c11 = __builtin_amdgcn_mfma_f32_32x32x16_bf16(ch1, dl1, c11, 0, 0, 0);
        c11 = __builtin_amdgcn_mfma_f32_32x32x16_bf16(cl1, dh1, c11, 0, 0, 0);
        ch0 = nh0; ch1 = nh1; cl0 = nl0; cl1 = nl1;
        dh0 = mh0; dl0 = ml0; dh1 = mh1; dl1 = ml1;
    }

#pragma unroll
    for (int r = 0; r < 16; ++r) {
        float s0 = fabsf(c00[r]) + fabsf(c01[r]);
        float s1 = fabsf(c10[r]) + fabsf(c11[r]);
#pragma unroll
        for (int m = 1; m <= 16; m <<= 1) { s0 += __shfl_xor(s0, m); s1 += __shfl_xor(s1, m); }
        if ((lane & 31) == 0) {
            int rowoff = (r & 3) + 8 * (r >> 2) + 4 * g;
            atomicAdd(&Pp[mbase + rowoff], s0);
            atomicAdd(&Pp[mbase + 32 + rowoff], s1);
        }
    }
    __syncthreads();
    if (t < 128) P[((size_t)b * 128 + t) * 128 + c] = Pp[t];
}

// ---------------- weight packing: W[N][K] -> [ct][kt][64] float4 ----------------
struct PackPtrs { const float* p[51]; };

__global__ void pack_k(PackPtrs pp, float4* __restrict__ dst) {
    int m = blockIdx.y;
    const float* src = pp.p[m];
    int N, K, KT; size_t off;
    if (m < 12)      { N = 384; K = 128; KT = 32; off = (size_t)m * 12288; }
    else if (m < 24) { N = 128; K = 128; KT = 32; off = 147456 + (size_t)(m - 12) * 4096; }
    else if (m < 36) { N = 128; K = 128; KT = 32; off = 196608 + (size_t)(m - 24) * 4096; }
    else if (m < 48) { N = 128; K = 128; KT = 32; off = 245760 + (size_t)(m - 36) * 4096; }
    else if (m == 48){ N = 128; K = 161; KT = 41; off = 294912; }
    else if (m == 49){ N = 128; K = 161; KT = 41; off = 300160; }
    else             { N = 512; K = 128; KT = 32; off = 305408; }
    int idx = blockIdx.x * 256 + threadIdx.x;
    int total = (N >> 6) * KT * 64;
    if (idx >= total) return;
    int ln = idx & 63;
    int kt = (idx >> 6) % KT;
    int ct = idx / (KT * 64);
    int cc = ct * 64 + ln;
    int k0 = kt * 4;
    float4 v;
    v.x = (k0 + 0 < K) ? src[(size_t)cc * K + k0 + 0] : 0.f;
    v.y = (k0 + 1 < K) ? src[(size_t)cc * K + k0 + 1] : 0.f;
    v.z = (k0 + 2 < K) ? src[(size_t)cc * K + k0 + 2] : 0.f;
    v.w = (k0 + 3 < K) ? src[(size_t)cc * K + k0 + 3] : 0.f;
    dst[off + idx] = v;
}

// ---------------- megakernel: 512 blocks x 256 threads, 2 rows/block ----------------
struct MegaArgs {
    const float* b_qkv[12]; const float* b_o[12]; const float* b1[12]; const float* b2[12];
    const float* ln1g[12]; const float* ln1b[12]; const float* ln2g[12]; const float* ln2b[12];
    const float* embed_b; const float* embed2_b; const float* env_w; const float* env_b;
    const float* samp_b;
    const float* posT; const float* ham; const float* P;
    const float4* Wp;
    float* KV;    // 2 parities x 1024 rows x 256 (K|V)
    float* envbuf; float* Y; float* out;
    unsigned* ctr;
};

struct __align__(16) SM {
    float KVs[64][129];                                    // 33 KB half-tile K/V
    union { float S[8][128]; float partial[16][128]; };    // 8 KB
    float Aq[2][128];
    float Ax[2][128];
    float Ax2[2][128];
    float Ah[2][128];
    float cv[2][176];
    float red2[16];
    int   red2i[8];
    float tvals[128], tout[128], Linv[8];
};

// per-batch barrier (64 blocks), fence-free (cross-block data via agent atomics)
__device__ __forceinline__ void gbarb(unsigned* ctr, unsigned& bi) {
    asm volatile("s_waitcnt vmcnt(0)" ::: "memory");
    __syncthreads();
    if (threadIdx.x == 0) {
        bi += 1;
        __hip_atomic_fetch_add(ctr, 1u, __ATOMIC_RELAXED, __HIP_MEMORY_SCOPE_AGENT);
        unsigned target = bi * 64u;
        while (__hip_atomic_load(ctr, __ATOMIC_RELAXED, __HIP_MEMORY_SCOPE_AGENT) < target) {
            __builtin_amdgcn_s_sleep(1);
        }
    }
    __syncthreads();
}

// 2-way K-split gemm: 256 threads, cidx=t&127, kq=t>>7; 2 activation rows
template <int NCB>
__device__ __forceinline__ void gemm_acc2(const float* A, int astride, const float4* Wp,
                                          int KT, int t, float (*acc)[2]) {
    int cidx = t & 127, kq = t >> 7;
    int KTq = (KT + 1) >> 1;
    int kt0 = kq * KTq;
    int kt1 = kt0 + KTq; if (kt1 > KT) kt1 = KT;
#pragma unroll
    for (int i = 0; i < NCB; ++i) { acc[i][0] = 0.f; acc[i][1] = 0.f; }
    for (int kt = kt0; kt < kt1; ++kt) {
        float4 a0 = *(const float4*)(A + 0 * astride + kt * 4);
        float4 a1 = *(const float4*)(A + 1 * astride + kt * 4);
#pragma unroll
        for (int i = 0; i < NCB; ++i) {
            int cb = cidx + i * 128;
            float4 w = Wp[((size_t)((cb >> 6) * KT + kt)) * 64 + (cb & 63)];
            acc[i][0] += a0.x * w.x + a0.y * w.y + a0.z * w.z + a0.w * w.w;
            acc[i][1] += a1.x * w.x + a1.y * w.y + a1.z * w.z + a1.w * w.w;
        }
    }
}

// fused reduce: write all partials, ONE sync; read with rdp()
template <int NCB>
__device__ __forceinline__ void gemm_red_write(const float (*acc)[2], int t, SM& sm) {
    int c = t & 127, kq = t >> 7;
#pragma unroll
    for (int i = 0; i < NCB; ++i)
#pragma unroll
        for (int r = 0; r < 2; ++r)
            sm.partial[(i * 2 + r) * 2 + kq][c] = acc[i][r];
    __syncthreads();
}
__device__ __forceinline__ float rdp(SM& sm, int i, int rr, int c) {
    return sm.partial[(i * 2 + rr) * 2 + 0][c] + sm.partial[(i * 2 + rr) * 2 + 1][c];
}

__device__ __forceinline__ float lnorm(float v, int t, const float* g, const float* be, SM& sm) {
    float s = v, s2 = v * v;
#pragma unroll
    for (int mm = 1; mm <= 32; mm <<= 1) { s += __shfl_xor(s, mm); s2 += __shfl_xor(s2, mm); }
    int w = t >> 6;
    if ((t & 63) == 0) { sm.red2[w * 2] = s; sm.red2[w * 2 + 1] = s2; }
    __syncthreads();
    int r = t >> 7;
    float S = sm.red2[(2 * r) * 2] + sm.red2[(2 * r + 1) * 2];
    float S2 = sm.red2[(2 * r) * 2 + 1] + sm.red2[(2 * r + 1) * 2 + 1];
    float mu = S * (1.f / 128.f);
    float var = S2 * (1.f / 128.f) - mu * mu;
    float res = (v - mu) * rsqrtf(var + 1e-5f) * g[t & 127] + be[t & 127];
    __syncthreads();
    return res;
}

__device__ __forceinline__ void qkv_tail(const MegaArgs& a, SM& sm, int l, int t, int rowbase) {
    const float4* qkvp = a.Wp + (size_t)l * 12288;
    float acc3[3][2];
    gemm_acc2<3>(&sm.Ax[0][0], 128, qkvp, 32, t, acc3);
    gemm_red_write<3>(acc3, t, sm);
    int c = t & 127, rr = t >> 7;
    const float* bq = a.b_qkv[l];
    float* KVp = a.KV + (size_t)(l & 1) * 262144;
    float vq = rdp(sm, 0, rr, c) + bq[c];
    sm.Aq[rr][c] = vq;
    float vk = rdp(sm, 1, rr, c) + bq[128 + c];
    ASTORE(&KVp[(size_t)(rowbase + rr) * 256 + c], vk);
    float vv = rdp(sm, 2, rr, c) + bq[256 + c];
    ASTORE(&KVp[(size_t)(rowbase + rr) * 256 + 128 + c], vv);
}

__global__ void __launch_bounds__(256, 2) mega_k(MegaArgs a) {
    __shared__ SM sm;
    const int t = threadIdx.x;
    const int bid = blockIdx.x;
    const int rowbase = bid * 2;
    const int b = rowbase >> 7;
    const int tfr = rowbase & 127;
    const int c = t & 127;
    const int rr = t >> 7;
    unsigned bctr = 0;
    unsigned* myctr = a.ctr + b * 16;

    const float4* embedp  = a.Wp + 294912;
    const float4* embed2p = a.Wp + 300160;
    const float4* sampp   = a.Wp + 305408;

    // ---- prologue: embed + qkv layer0 ----
    {
        int tf = tfr + rr;
        for (int j = c; j < 176; j += 128) {
            float val = 0.f;
            if (j < 33) val = a.posT[tf * 33 + j];
            else if (j < 161) {
                int o = j - 33;
                float p1 = a.P[((size_t)(b * 128 + o)) * 128 + tf];
                float p0 = (tf > 0) ? a.P[((size_t)(b * 128 + o)) * 128 + tf - 1] : 0.f;
                val = (p0 + p1) * (1.f / 512.f);
            }
            sm.cv[rr][j] = val;
        }
        __syncthreads();
        float acc1[1][2];
        gemm_acc2<1>(&sm.cv[0][0], 176, embedp, 41, t, acc1);
        gemm_red_write<1>(acc1, t, sm);
        float v = rdp(sm, 0, rr, c) + a.embed_b[c];
        sm.Ax[rr][c] = v;
        __syncthreads();
        qkv_tail(a, sm, 0, t, rowbase);
        gbarb(myctr, bctr);
    }

    for (int l = 0; l < 12; ++l) {
        if (l == 6) {
            // ---- mid: env softmax + top16 + embed2 + qkv dec0 ----
            float v = (t < 128) ? ALOAD(&a.envbuf[b * 128 + t]) : -1e30f;
            float m_ = v;
#pragma unroll
            for (int mm = 1; mm <= 32; mm <<= 1) m_ = fmaxf(m_, __shfl_xor(m_, mm));
            if ((t & 63) == 0) sm.red2[(t >> 6) * 2] = m_;
            __syncthreads();
            float mx = fmaxf(sm.red2[0], sm.red2[2]);
            float e = (t < 128) ? expf(v - mx) : 0.f;
            float ssum = e;
#pragma unroll
            for (int mm = 1; mm <= 32; mm <<= 1) ssum += __shfl_xor(ssum, mm);
            __syncthreads();
            if ((t & 63) == 0) sm.red2[(t >> 6) * 2 + 1] = ssum;
            __syncthreads();
            float lsum = sm.red2[1] + sm.red2[3];
            if (t < 128) { sm.tvals[t] = e / lsum; sm.tout[t] = 0.f; }
            __syncthreads();
            for (int it = 0; it < 16; ++it) {
                float cv_ = (t < 128) ? sm.tvals[t] : -2.f;
                int ci = t & 127;
#pragma unroll
                for (int mm = 1; mm <= 32; mm <<= 1) {
                    float ov = __shfl_xor(cv_, mm);
                    int oi = __shfl_xor(ci, mm);
                    if (ov > cv_ || (ov == cv_ && oi < ci)) { cv_ = ov; ci = oi; }
                }
                if ((t & 63) == 0) { sm.red2[(t >> 6) * 2] = cv_; sm.red2i[t >> 6] = ci; }
                __syncthreads();
                if (t == 0) {
                    float v0 = sm.red2[0], v1 = sm.red2[2];
                    int i0 = sm.red2i[0], i1 = sm.red2i[1];
                    float bv; int bi2;
                    if (v1 > v0 || (v1 == v0 && i1 < i0)) { bv = v1; bi2 = i1; }
                    else { bv = v0; bi2 = i0; }
                    sm.tout[bi2] = bv;
                    sm.tvals[bi2] = -3.f;
                }
                __syncthreads();
            }
            float sclr = sm.tout[tfr + rr];
            for (int j = c; j < 176; j += 128) {
                float val = 0.f;
                if (j < 33) val = a.posT[(tfr + rr) * 33 + j];
                else if (j < 161) val = sm.Ax[rr][j - 33] * sclr;
                sm.cv[rr][j] = val;
            }
            __syncthreads();
            float acc1[1][2];
            gemm_acc2<1>(&sm.cv[0][0], 176, embed2p, 41, t, acc1);
            gemm_red_write<1>(acc1, t, sm);
            float vv = rdp(sm, 0, rr, c) + a.embed2_b[c];
            sm.Ax[rr][c] = vv;
            __syncthreads();
            qkv_tail(a, sm, 6, t, rowbase);
            gbarb(myctr, bctr);
        }

        const float4* op  = a.Wp + 147456 + (size_t)l * 4096;
        const float4* w1p = a.Wp + 196608 + (size_t)l * 4096;
        const float4* w2p = a.Wp + 245760 + (size_t)l * 4096;
        const float* KVg = a.KV + (size_t)(l & 1) * 262144 + (size_t)b * 32768;

        // ---- attention: half-staged K/V, reg-pipelined loads ----
        {
            const float scl = 0.17677669529663687f;
            float rg[32], rg2[32];
            float oacc = 0.f;
            // P1: load+write K half0, issue K half1
#pragma unroll
            for (int j = 0; j < 32; ++j)
                rg[j] = ALOAD(&KVg[(size_t)(2 * j + rr) * 256 + c]);
#pragma unroll
            for (int j = 0; j < 32; ++j) sm.KVs[2 * j + rr][c] = rg[j];
#pragma unroll
            for (int j = 0; j < 32; ++j)
                rg2[j] = ALOAD(&KVg[(size_t)(64 + 2 * j + rr) * 256 + c]);
            __syncthreads();
            // P2: QK half0
            {
                int k = t & 63, h = t >> 6;
                float s0 = 0.f, s1 = 0.f;
#pragma unroll 8
                for (int d = 0; d < 32; ++d) {
                    float kv = sm.KVs[k][h * 32 + d];
                    s0 += sm.Aq[0][h * 32 + d] * kv;
                    s1 += sm.Aq[1][h * 32 + d] * kv;
                }
                sm.S[0 + h][k] = s0 * scl;
                sm.S[4 + h][k] = s1 * scl;
            }
            __syncthreads();
            // P3: write K half1, issue V half0
#pragma unroll
            for (int j = 0; j < 32; ++j) sm.KVs[2 * j + rr][c] = rg2[j];
#pragma unroll
            for (int j = 0; j < 32; ++j)
                rg[j] = ALOAD(&KVg[(size_t)(2 * j + rr) * 256 + 128 + c]);
            __syncthreads();
            // P4: QK half1
            {
                int k = t & 63, h = t >> 6;
                float s0 = 0.f, s1 = 0.f;
#pragma unroll 8
                for (int d = 0; d < 32; ++d) {
                    float kv = sm.KVs[k][h * 32 + d];
                    s0 += sm.Aq[0][h * 32 + d] * kv;
                    s1 += sm.Aq[1][h * 32 + d] * kv;
                }
                sm.S[0 + h][64 + k] = s0 * scl;
                sm.S[4 + h][64 + k] = s1 * scl;
            }
            __syncthreads();
            // P5: write V half0, softmax, issue V half1
#pragma unroll
            for (int j = 0; j < 32; ++j) sm.KVs[2 * j + rr][c] = rg[j];
            {
                int row = t >> 5, l32 = t & 31;
                float v0 = sm.S[row][l32], v1 = sm.S[row][l32 + 32];
                float v2 = sm.S[row][l32 + 64], v3 = sm.S[row][l32 + 96];
                float mx = fmaxf(fmaxf(v0, v1), fmaxf(v2, v3));
#pragma unroll
                for (int mm = 1; mm <= 16; mm <<= 1) mx = fmaxf(mx, __shfl_xor(mx, mm));
                float e0 = __expf(v0 - mx), e1 = __expf(v1 - mx);
                float e2 = __expf(v2 - mx), e3 = __expf(v3 - mx);
                float ls = e0 + e1 + e2 + e3;
#pragma unroll
                for (int mm = 1; mm <= 16; mm <<= 1) ls += __shfl_xor(ls, mm);
                sm.S[row][l32] = e0; sm.S[row][l32 + 32] = e1;
                sm.S[row][l32 + 64] = e2; sm.S[row][l32 + 96] = e3;
                if (l32 == 0) sm.Linv[row] = 1.f / ls;
            }
#pragma unroll
            for (int j = 0; j < 32; ++j)
                rg2[j] = ALOAD(&KVg[(size_t)(64 + 2 * j + rr) * 256 + 128 + c]);
            __syncthreads();
            // P6: PV half0
            {
                int r = t >> 7, h = (t >> 5) & 3, d = t & 31;
                const float* Pr = &sm.S[r * 4 + h][0];
#pragma unroll 8
                for (int k2 = 0; k2 < 64; ++k2) oacc += Pr[k2] * sm.KVs[k2][h * 32 + d];
            }
            __syncthreads();
            // P7: write V half1
#pragma unroll
            for (int j = 0; j < 32; ++j) sm.KVs[2 * j + rr][c] = rg2[j];
            __syncthreads();
            // P8: PV half1 + Ah
            {
                int r = t >> 7, h = (t >> 5) & 3, d = t & 31;
                const float* Pr = &sm.S[r * 4 + h][64];
#pragma unroll 8
                for (int k2 = 0; k2 < 64; ++k2) oacc += Pr[k2] * sm.KVs[k2][h * 32 + d];
                sm.Ah[r][h * 32 + d] = oacc * sm.Linv[r * 4 + h];
            }
            __syncthreads();
        }
        // ---- o-proj + residual + ln1 ----
        {
            float ac[1][2];
            gemm_acc2<1>(&sm.Ah[0][0], 128, op, 32, t, ac);
            gemm_red_write<1>(ac, t, sm);
            float v = rdp(sm, 0, rr, c) + a.b_o[l][c] + sm.Ax[rr][c];
            v = lnorm(v, t, a.ln1g[l], a.ln1b[l], sm);
            sm.Ax2[rr][c] = v;
            __syncthreads();
        }
        // ---- ffn1 ----
        {
            float ac[1][2];
            gemm_acc2<1>(&sm.Ax2[0][0], 128, w1p, 32, t, ac);
            gemm_red_write<1>(ac, t, sm);
            float v = fmaxf(rdp(sm, 0, rr, c) + a.b1[l][c], 0.f);
            sm.Ah[rr][c] = v;
            __syncthreads();
        }
        // ---- ffn2 + residual + ln2 ----
        {
            float ac[1][2];
            gemm_acc2<1>(&sm.Ah[0][0], 128, w2p, 32, t, ac);
            gemm_red_write<1>(ac, t, sm);
            float v2 = rdp(sm, 0, rr, c) + a.b2[l][c] + sm.Ax2[rr][c];
            v2 = lnorm(v2, t, a.ln2g[l], a.ln2b[l], sm);
            sm.Ax[rr][c] = v2;
            __syncthreads();
        }
        // ---- tail ----
        if (l == 5) {
            float pv = sm.Ax[rr][c] * a.env_w[c];
#pragma unroll
            for (int mm = 1; mm <= 32; mm <<= 1) pv += __shfl_xor(pv, mm);
            int w = t >> 6;
            if ((t & 63) == 0) sm.red2[w * 2] = pv;
            __syncthreads();
            if (t < 2) ASTORE(&a.envbuf[rowbase + t],
                              sm.red2[(2 * t) * 2] + sm.red2[(2 * t + 1) * 2] + a.env_b[0]);
            __syncthreads();
        } else if (l == 11) {
            float ac4[4][2];
            gemm_acc2<4>(&sm.Ax[0][0], 128, sampp, 32, t, ac4);
            gemm_red_write<4>(ac4, t, sm);
#pragma unroll
            for (int i = 0; i < 4; ++i) {
                int cg = c + i * 128;
                float v = (rdp(sm, i, rr, c) + a.samp_b[cg]) * a.ham[cg];
                ASTORE(&a.Y[((size_t)(rowbase + rr)) * 512 + cg], v);
            }
        } else {
            qkv_tail(a, sm, l + 1, t, rowbase);
        }
        gbarb(myctr, bctr);
    }

    // ---- overlap-add (batch-local) ----
    {
        int b64 = bid & 63;
#pragma unroll
        for (int i = 0; i < 2; ++i) {
            int il = b64 * 256 + t + i * 16384;
            int t0 = il >> 8, w0 = il & 255;
            float acc = ALOAD(&a.Y[((size_t)(b * 128 + t0)) * 512 + w0]);
            if (t0 > 0) acc += ALOAD(&a.Y[((size_t)(b * 128 + t0 - 1)) * 512 + w0 + 256]);
            a.out[(size_t)b * 32768 + il] = acc;
        }
    }
}

extern "C" void kernel_launch(void* const* d_in, const int* in_sizes, int n_in,
                              void* d_out, int out_size, void* d_ws, size_t ws_size,
                              hipStream_t stream) {
    const float* x        = (const float*)d_in[0];
    const float* filters  = (const float*)d_in[1];
    const float* embed_w  = (const float*)d_in[2];
    const float* embed_b  = (const float*)d_in[3];
    const float* embed2_w = (const float*)d_in[4];
    const float* embed2_b = (const float*)d_in[5];
    const float* env_w    = (const float*)d_in[6];
    const float* env_b    = (const float*)d_in[7];
    const float* samp_w   = (const float*)d_in[8];
    const float* samp_b   = (const float*)d_in[9];

    float* ws = (float*)d_ws;
    float* P     = ws;                      // 131072
    float* posT  = ws + 131072;             // 4352
    float* hamw  = ws + 135424;             // 512
    float* envb  = ws + 135936;             // 1024
    float* KV    = ws + 136960;             // 524288 (2 parities x 1024 x 256)
    float* Y     = ws + 661248;             // 524288
    float4* Wp   = (float4*)(ws + 1185536); // 321792 float4
    unsigned* ctr = (unsigned*)(ws + 2472704);
    // conv-prep aliases (dead regions at conv time)
    unsigned short* xhi = (unsigned short*)Y;
    unsigned short* xlo = (unsigned short*)(Y + 131072);
    unsigned short* Fph = (unsigned short*)KV;
    unsigned short* Fpl = (unsigned short*)(KV + 32768);

    pos_k<<<1, 512, 0, stream>>>(posT, hamw);
    bfsplit_k<<<1024, 256, 0, stream>>>(x, xhi, xlo, NB * NS);
    fpack_k<<<256, 256, 0, stream>>>(filters, Fph, Fpl);
    conv_mfma_k<<<dim3(128, 8), 512, 0, stream>>>(xhi, xlo, Fph, Fpl, P);

    PackPtrs pp;
    for (int l = 0; l < 12; ++l) {
        int base = (l < 6) ? 10 + l * 12 : 82 + (l - 6) * 12;
        pp.p[l]      = (const float*)d_in[base + 0];
        pp.p[12 + l] = (const float*)d_in[base + 2];
        pp.p[24 + l] = (const float*)d_in[base + 4];
        pp.p[36 + l] = (const float*)d_in[base + 6];
    }
    pp.p[48] = embed_w; pp.p[49] = embed2_w; pp.p[50] = samp_w;
    pack_k<<<dim3(64, 51), 256, 0, stream>>>(pp, Wp);

    hipMemsetAsync(ctr, 0, 1024, stream);

    MegaArgs ma;
    for (int l = 0; l < 12; ++l) {
        int base = (l < 6) ? 10 + l * 12 : 82 + (l - 6) * 12;
        ma.b_qkv[l] = (const float*)d_in[base + 1];
        ma.b_o[l]   = (const float*)d_in[base + 3];
        ma.b1[l]    = (const float*)d_in[base + 5];
        ma.b2[l]    = (const float*)d_in[base + 7];
        ma.ln1g[l]  = (const float*)d_in[base + 8];
        ma.ln1b[l]  = (const float*)d_in[base + 9];
        ma.ln2g[l]  = (const float*)d_in[base + 10];
        ma.ln2b[l]  = (const float*)d_in[base + 11];
    }
    ma.embed_b = embed_b; ma.embed2_b = embed2_b;
    ma.env_w = env_w; ma.env_b = env_b; ma.samp_b = samp_b;
    ma.posT = posT; ma.ham = hamw; ma.P = P;
    ma.Wp = (const float4*)Wp;
    ma.KV = KV; ma.envbuf = envb; ma.Y = Y; ma.out = (float*)d_out;
    ma.ctr = ctr;

    mega_k<<<512, 256, 0, stream>>>(ma);
}